// Round 7
// baseline (409.436 us; speedup 1.0000x reference)
//
#include <hip/hip_runtime.h>
#include <cstdint>
#include <cstddef>

#pragma clang fp contract(off)

typedef unsigned long long u64;

#define NB 32
#define NA 9
#define NH 128
#define NW 128
#define HW (NH*NW)            // 16384
#define NANCH (NA*HW)         // 147456
#define PRE_N 6000
#define POST_N 300
#define CAND_CAP 8192
#define NMS_T 0.7f
#define GX_GATHER 24          // blocks per image in k_gather

// Base anchor widths/heights (generate_anchors(16,[.5,1,2],[8,16,32])).
// All anchor centers are at (w*16+8, h*16+8) exactly (fp32-exact integers).
__constant__ float c_wa[9] = {184.f,368.f,736.f,128.f,256.f,512.f,88.f,176.f,352.f};
__constant__ float c_ha[9] = {96.f,192.f,384.f,128.f,256.f,512.f,176.f,352.f,704.f};

__device__ __forceinline__ float4 decode_clip(int a, int h, int w,
    float dx, float dy, float dlw, float dlh, float imh, float imw) {
  float wa = c_wa[a], ha = c_ha[a];
  float cx = (float)w * 16.0f + 8.0f;
  float cy = (float)h * 16.0f + 8.0f;
  float pcx = dx * wa + cx;
  float pcy = dy * ha + cy;
  float pw = expf(dlw) * wa;
  float ph = expf(dlh) * ha;
  float x1 = pcx - 0.5f * pw;
  float y1 = pcy - 0.5f * ph;
  float x2 = pcx + 0.5f * pw;
  float y2 = pcy + 0.5f * ph;
  float4 r;
  r.x = fminf(fmaxf(x1, 0.0f), imw - 1.0f);
  r.y = fminf(fmaxf(y1, 0.0f), imh - 1.0f);
  r.z = fminf(fmaxf(x2, 0.0f), imw - 1.0f);
  r.w = fminf(fmaxf(y2, 0.0f), imh - 1.0f);
  return r;
}

__device__ __forceinline__ unsigned score_key(float sc, float bw, float bh, float msz) {
  unsigned bits = __float_as_uint(sc);
  unsigned key = (bits & 0x80000000u) ? ~bits : (bits | 0x80000000u);
  if (!(bw >= msz && bh >= msz)) key = 0u;   // filtered == score NEG_INF
  return key;
}

// earlier/picked box (p,pa) vs candidate (v,ar):
// reference iou = inter / max(pa + ar - inter, 1e-6)
__device__ __forceinline__ bool sup_test4(float4 v, float ar, float4 p, float pa) {
  float xx1 = fmaxf(p.x, v.x), yy1 = fmaxf(p.y, v.y);
  float xx2 = fminf(p.z, v.z), yy2 = fminf(p.w, v.w);
  float iw = fmaxf(xx2 - xx1 + 1.0f, 0.0f);
  float ih = fmaxf(yy2 - yy1 + 1.0f, 0.0f);
  float inter = iw * ih;
  float iou = inter / fmaxf(pa + ar - inter, 1e-6f);
  return iou > NMS_T;
}

// ---- inline radix-select helpers (256-thread blocks) -----------------------
// Find coarse bin B (top-12) where from-top cumulative crosses PRE_N.
__device__ void find_B(const unsigned* __restrict__ hb, unsigned* part,
                       unsigned* outB, unsigned* outCum) {
  int tid = threadIdx.x;
  unsigned s = 0;
  for (int i = 0; i < 16; ++i) s += hb[tid*16 + i];
  part[tid] = s;
  __syncthreads();
  for (int off = 1; off < 256; off <<= 1) {
    unsigned v = (tid + off < 256) ? part[tid + off] : 0u;
    __syncthreads();
    part[tid] += v;
    __syncthreads();
  }
  unsigned St = part[tid];
  unsigned Sn = (tid < 255) ? part[tid + 1] : 0u;
  if (St >= (unsigned)PRE_N && Sn < (unsigned)PRE_N) {
    unsigned cum = Sn, B = 0, cumAbove = Sn;
    for (int i = 15; i >= 0; --i) {
      unsigned v = hb[tid*16 + i];
      if (cum + v >= (unsigned)PRE_N) { B = (unsigned)(tid*16 + i); cumAbove = cum; break; }
      cum += v;
    }
    *outB = B; *outCum = cumAbove;
  }
  __syncthreads();
}

// Final 24-bit threshold from refine histogram hb2, given B and cum0.
__device__ void find_thr(const unsigned* __restrict__ hb2, unsigned B, unsigned cum0,
                         unsigned* part, unsigned* outThr) {
  int tid = threadIdx.x;
  unsigned s = 0;
  for (int i = 0; i < 16; ++i) s += hb2[tid*16 + i];
  part[tid] = s;
  __syncthreads();
  for (int off = 1; off < 256; off <<= 1) {
    unsigned v = (tid + off < 256) ? part[tid + off] : 0u;
    __syncthreads();
    part[tid] += v;
    __syncthreads();
  }
  unsigned St = cum0 + part[tid];
  unsigned Sn = cum0 + ((tid < 255) ? part[tid + 1] : 0u);
  if (St >= (unsigned)PRE_N && Sn < (unsigned)PRE_N) {
    unsigned cum = Sn, t = 1u;
    for (int i = 15; i >= 0; --i) {
      unsigned v = hb2[tid*16 + i];
      if (cum + v >= (unsigned)PRE_N) {
        t = (B << 20) | ((unsigned)(tid*16 + i) << 8);
        break;
      }
      cum += v;
    }
    if (t == 0u) t = 1u;
    *outThr = t;
  }
  __syncthreads();
}

// K1: decode+filter -> order-preserving uint key per anchor, fused coarse
// histogram (key>>20, 4096 bins). One anchor per block: grid (16, 9, 32).
__global__ __launch_bounds__(256) void k_keys(const float* __restrict__ cls,
    const float* __restrict__ dl, const float* __restrict__ info,
    unsigned* __restrict__ keys, unsigned* __restrict__ hist) {
  __shared__ unsigned hsh[4096];
  int tid = threadIdx.x;
  for (int i = tid; i < 4096; i += 256) hsh[i] = 0;
  int a = blockIdx.y, b = blockIdx.z;
  int t = blockIdx.x * 256 + tid;            // 0..4095
  int hw0 = t * 4;                           // 4 consecutive hw, same row
  int h = hw0 >> 7;
  const float* dlb  = dl  + (size_t)b * (4*NA*HW);
  const float* clsb = cls + (size_t)b * (2*NA*HW);
  float imh = info[b*3+0], imw = info[b*3+1];
  float msz = 16.0f * info[b*3+2];
  unsigned* kb = keys + (size_t)b * NANCH;
  __syncthreads();
  float4 dx4 = *(const float4*)&dlb[(a*4+0)*HW + hw0];
  float4 dy4 = *(const float4*)&dlb[(a*4+1)*HW + hw0];
  float4 dw4 = *(const float4*)&dlb[(a*4+2)*HW + hw0];
  float4 dh4 = *(const float4*)&dlb[(a*4+3)*HW + hw0];
  float4 sc4 = *(const float4*)&clsb[(NA+a)*HW + hw0];
  uint4 out;
  {
    float4 bx = decode_clip(a, h, (hw0+0)&127, dx4.x, dy4.x, dw4.x, dh4.x, imh, imw);
    out.x = score_key(sc4.x, bx.z-bx.x+1.0f, bx.w-bx.y+1.0f, msz);
  }
  {
    float4 bx = decode_clip(a, h, (hw0+1)&127, dx4.y, dy4.y, dw4.y, dh4.y, imh, imw);
    out.y = score_key(sc4.y, bx.z-bx.x+1.0f, bx.w-bx.y+1.0f, msz);
  }
  {
    float4 bx = decode_clip(a, h, (hw0+2)&127, dx4.z, dy4.z, dw4.z, dh4.z, imh, imw);
    out.z = score_key(sc4.z, bx.z-bx.x+1.0f, bx.w-bx.y+1.0f, msz);
  }
  {
    float4 bx = decode_clip(a, h, (hw0+3)&127, dx4.w, dy4.w, dw4.w, dh4.w, imh, imw);
    out.w = score_key(sc4.w, bx.z-bx.x+1.0f, bx.w-bx.y+1.0f, msz);
  }
  *(uint4*)&kb[a*HW + hw0] = out;
  atomicAdd(&hsh[out.x >> 20], 1u);
  atomicAdd(&hsh[out.y >> 20], 1u);
  atomicAdd(&hsh[out.z >> 20], 1u);
  atomicAdd(&hsh[out.w >> 20], 1u);
  __syncthreads();
  unsigned* gb = hist + ((size_t)b << 12);
  for (int i = tid; i < 4096; i += 256) {
    unsigned v = hsh[i];
    if (v) atomicAdd(&gb[i], v);
  }
}

// K2: refine histogram — bits[19:8] of keys whose top-12 == B (B inline from h1).
__global__ __launch_bounds__(256) void k_hist2(const unsigned* __restrict__ keys,
    const unsigned* __restrict__ hist1, unsigned* __restrict__ hist2) {
  __shared__ unsigned h[4096];
  __shared__ unsigned part[256];
  __shared__ unsigned sB, sCum;
  int b = blockIdx.y, tid = threadIdx.x;
  for (int i = tid; i < 4096; i += 256) h[i] = 0;
  __syncthreads();
  find_B(hist1 + ((size_t)b << 12), part, &sB, &sCum);
  unsigned B = sB;
  const unsigned* kb = keys + (size_t)b * NANCH;
  for (int i = blockIdx.x * 256 + tid; i < NANCH; i += gridDim.x * 256) {
    unsigned k = kb[i];
    if ((k >> 20) == B) atomicAdd(&h[(k >> 8) & 4095u], 1u);
  }
  __syncthreads();
  unsigned* gb = hist2 + ((size_t)b << 12);
  for (int i = tid; i < 4096; i += 256) { unsigned v = h[i]; if (v) atomicAdd(&gb[i], v); }
}

// K3: gather (key, ~origidx) for key >= thr (thr inline from h1+h2).
__global__ __launch_bounds__(256) void k_gather(const unsigned* __restrict__ keys,
    const unsigned* __restrict__ hist1, const unsigned* __restrict__ hist2,
    unsigned* __restrict__ cnt, u64* __restrict__ cand) {
  int b = blockIdx.y, tid = threadIdx.x;
  int lane = tid & 63, wv = tid >> 6;
  __shared__ unsigned part[256];
  __shared__ unsigned sB, sCum, sThr;
  __shared__ unsigned wcnt[4], woff[4], blkbase;
  if (tid == 0) sThr = 1u;
  __syncthreads();
  find_B(hist1 + ((size_t)b << 12), part, &sB, &sCum);
  find_thr(hist2 + ((size_t)b << 12), sB, sCum, part, &sThr);
  unsigned t_ = sThr;
  const unsigned* kb = keys + (size_t)b * NANCH;
  u64* cb = cand + (size_t)b * CAND_CAP;
  unsigned* cp = cnt + (size_t)b * 64;
  const int PER_BLK = NANCH / GX_GATHER;      // 6144
  int base0 = blockIdx.x * PER_BLK;
  for (int it = 0; it < PER_BLK / 256; ++it) {
    int j = base0 + it * 256 + tid;
    unsigned key = kb[j];
    bool pass = key >= t_;
    u64 mask = __ballot(pass);
    if (lane == 0) wcnt[wv] = (unsigned)__popcll(mask);
    __syncthreads();
    if (tid == 0) {
      unsigned s0 = 0;
      for (int w = 0; w < 4; ++w) { woff[w] = s0; s0 += wcnt[w]; }
      blkbase = s0 ? atomicAdd(cp, s0) : 0u;
    }
    __syncthreads();
    if (pass) {
      unsigned pos = blkbase + woff[wv] + (unsigned)__popcll(mask & ((1ull << lane) - 1ull));
      if (pos < CAND_CAP) {
        int a = j >> 14, hw = j & (HW - 1);
        unsigned oi = (unsigned)(hw * 9 + a);
        cb[pos] = ((u64)key << 32) | (unsigned)(~oi);
      }
    }
    __syncthreads();
  }
}

// K4: local sort of 2048-chunks (masks unwritten slots to 0 via cnt —
// no cand memset needed). 128 blocks. Chunk c: desc iff c even.
__global__ __launch_bounds__(256) void k_sortA(u64* __restrict__ cand,
                                               const unsigned* __restrict__ cnt) {
  __shared__ u64 sm[2048];   // 16 KiB
  int blk = blockIdx.x;
  int b = blk >> 2, c = blk & 3;
  unsigned effcnt = cnt[b * 64];
  if (effcnt > CAND_CAP) effcnt = CAND_CAP;
  u64* cb = cand + (size_t)b * CAND_CAP + (size_t)c * 2048;
  int base = c * 2048;
  int tid = threadIdx.x;
  for (int t = tid; t < 2048; t += 256)
    sm[t] = ((unsigned)(base + t) < effcnt) ? cb[t] : 0ull;
  bool blkdesc = (c & 1) == 0;
  for (int k = 2; k <= 2048; k <<= 1) {
    for (int j = k >> 1; j > 0; j >>= 1) {
      __syncthreads();
      for (int t = tid; t < 2048; t += 256) {
        int p = t ^ j;
        if (p > t) {
          bool up = (k == 2048) ? blkdesc : ((t & k) == 0);
          u64 x = sm[t], y = sm[p];
          if (up ? (x < y) : (x > y)) { sm[t] = y; sm[p] = x; }
        }
      }
    }
  }
  __syncthreads();
  for (int t = tid; t < 2048; t += 256) cb[t] = sm[t];
}

// K5: merge stages k=4096 and k=8192 in one block (all 8192 in LDS) + decode.
__global__ __launch_bounds__(1024) void k_sortF(u64* __restrict__ cand,
    const float* __restrict__ dl, const float* __restrict__ info,
    float4* __restrict__ boxes) {
  __shared__ u64 sm[CAND_CAP];   // 64 KiB
  int b = blockIdx.x, tid = threadIdx.x;
  u64* cb = cand + (size_t)b * CAND_CAP;
  for (int t = tid; t < CAND_CAP; t += 1024) sm[t] = cb[t];
  for (int k = 4096; k <= CAND_CAP; k <<= 1) {
    for (int j = k >> 1; j > 0; j >>= 1) {
      __syncthreads();
      for (int t = tid; t < CAND_CAP; t += 1024) {
        int p = t ^ j;
        if (p > t) {
          bool desc = (k == CAND_CAP) ? true : ((t & k) == 0);
          u64 x = sm[t], y = sm[p];
          if (desc ? (x < y) : (x > y)) { sm[t] = y; sm[p] = x; }
        }
      }
    }
  }
  __syncthreads();
  const float* dlb = dl + (size_t)b * (4*NA*HW);
  float imh = info[b*3+0], imw = info[b*3+1];
  for (int t = tid; t < PRE_N; t += 1024) {
    u64 ck = sm[t];
    cb[t] = ck;                                 // sorted order for k_nms
    float4 bx = make_float4(0.f, 0.f, 0.f, 0.f);
    if ((unsigned)(ck >> 32) != 0u) {
      int i = (int)(~(unsigned)(ck & 0xFFFFFFFFull));
      int a = i % 9, hw = i / 9;
      int h = hw >> 7, w = hw & 127;
      bx = decode_clip(a, h, w,
                       dlb[(a*4+0)*HW + hw], dlb[(a*4+1)*HW + hw],
                       dlb[(a*4+2)*HW + hw], dlb[(a*4+3)*HW + hw], imh, imw);
    }
    boxes[(size_t)b * PRE_N + t] = bx;
  }
}

// ---------- K6: blocked greedy NMS, 1024 threads = 256 cand x 4 segments ----
__global__ __launch_bounds__(1024) void k_nms(const u64* __restrict__ cand,
    const float4* __restrict__ boxes, float* __restrict__ out) {
  int b = blockIdx.x, tid = threadIdx.x;
  int c = tid & 255, seg = tid >> 8;     // candidate slot, column/kept segment
  int lane = tid & 63, wv = tid >> 6;    // 16 waves; seg is wave-uniform
  int cg = c >> 6;                       // candidate's 64-group
  __shared__ float4 kbox[POST_N];
  __shared__ float  karea[POST_N];
  __shared__ float4 cbox[256];
  __shared__ float  carea[256];
  __shared__ unsigned supf[256];         // 0 = alive; nonzero = dead/invalid
  __shared__ u64 sup[256][4];
  __shared__ u64 aliveM[4];
  __shared__ u64 kgW[4];
  __shared__ int s_nk;
  if (tid == 0) s_nk = 0;
  __syncthreads();
  const u64* cb = cand + (size_t)b * CAND_CAP;
  const float4* bb = boxes + (size_t)b * PRE_N;
  float* ob = out + (size_t)b * (POST_N * 5);
  volatile unsigned* svf = supf;

  for (int base = 0; base < PRE_N; base += 256) {
    // load chunk (first 256 threads)
    if (tid < 256) {
      int i = base + tid;
      u64 ck = (i < PRE_N) ? cb[i] : 0ull;
      bool valid = (unsigned)(ck >> 32) != 0u;
      float4 v = valid ? bb[i] : make_float4(0.f, 0.f, 0.f, 0.f);
      cbox[tid] = v;
      carea[tid] = (v.z - v.x + 1.0f) * (v.w - v.y + 1.0f);
      supf[tid] = valid ? 0u : 1u;
    }
    __syncthreads();                                          // B1
    int nk0 = s_nk;

    // pre-filter vs kept list: 4-way split of depth, cross-segment poll
    if (supf[c] == 0u) {
      float4 v = cbox[c]; float ar = carea[c];
      for (int k = seg; k < nk0; k += 4) {
        if (svf[c]) break;
        if (sup_test4(v, ar, kbox[k], karea[k])) { atomicOr(&supf[c], 1u); break; }
      }
    }
    __syncthreads();                                          // B2

    // alive ballots (seg-0 waves = waves 0..3, group = wv)
    if (seg == 0) {
      u64 am = __ballot(supf[c] == 0u);
      if (lane == 0) aliveM[wv] = am;
    }
    __syncthreads();                                          // B3
    if ((aliveM[0] | aliveM[1] | aliveM[2] | aliveM[3]) == 0ull) continue;

    // intra-chunk suppression matrix: thread (c,seg) -> sup[c][seg]
    if (supf[c] == 0u && seg <= cg) {
      float4 v = cbox[c]; float ar = carea[c];
      u64 m = aliveM[seg];
      if (seg == cg) m &= (1ull << (c & 63)) - 1ull;   // strictly earlier
      u64 r = 0;
      while (m) {
        int j = __builtin_ctzll(m);
        m &= m - 1;
        int col = seg * 64 + j;
        if (sup_test4(v, ar, cbox[col], carea[col])) r |= 1ull << j;
      }
      sup[c][seg] = r;
    }
    __syncthreads();                                          // B4

    // resolve by wave 0: greedy within chunk, hierarchical over 4 groups
    if (wv == 0) {
      u64 kw0 = 0, kw1 = 0, kw2 = 0, kw3 = 0;
      {
        bool a = (aliveM[0] >> lane) & 1;
        u64 r = a ? sup[lane][0] : 0;
        u64 cm = __ballot(a), kg = 0;
        while (cm) {
          int j = __builtin_ctzll(cm);
          kg |= 1ull << j;
          u64 rem = __ballot((r >> j) & 1);
          cm &= ~(rem | (1ull << j));
        }
        kw0 = kg;
      }
      {
        int cc = 64 + lane;
        bool a = (aliveM[1] >> lane) & 1;
        if (a) a = (sup[cc][0] & kw0) == 0;
        u64 r = a ? sup[cc][1] : 0;
        u64 cm = __ballot(a), kg = 0;
        while (cm) {
          int j = __builtin_ctzll(cm);
          kg |= 1ull << j;
          u64 rem = __ballot((r >> j) & 1);
          cm &= ~(rem | (1ull << j));
        }
        kw1 = kg;
      }
      {
        int cc = 128 + lane;
        bool a = (aliveM[2] >> lane) & 1;
        if (a) a = ((sup[cc][0] & kw0) == 0) && ((sup[cc][1] & kw1) == 0);
        u64 r = a ? sup[cc][2] : 0;
        u64 cm = __ballot(a), kg = 0;
        while (cm) {
          int j = __builtin_ctzll(cm);
          kg |= 1ull << j;
          u64 rem = __ballot((r >> j) & 1);
          cm &= ~(rem | (1ull << j));
        }
        kw2 = kg;
      }
      {
        int cc = 192 + lane;
        bool a = (aliveM[3] >> lane) & 1;
        if (a) a = ((sup[cc][0] & kw0) == 0) && ((sup[cc][1] & kw1) == 0) &&
                   ((sup[cc][2] & kw2) == 0);
        u64 r = a ? sup[cc][3] : 0;
        u64 cm = __ballot(a), kg = 0;
        while (cm) {
          int j = __builtin_ctzll(cm);
          kg |= 1ull << j;
          u64 rem = __ballot((r >> j) & 1);
          cm &= ~(rem | (1ull << j));
        }
        kw3 = kg;
      }
      if (lane == 0) { kgW[0] = kw0; kgW[1] = kw1; kgW[2] = kw2; kgW[3] = kw3; }
    }
    __syncthreads();                                          // B5

    // append kept boxes + update s_nk in one phase (uses nk0 register)
    if (tid < 256) {
      u64 kgw = kgW[wv];
      bool kept = (kgw >> lane) & 1;
      int pre = 0;
      for (int g = 0; g < wv; ++g) pre += (int)__popcll(kgW[g]);
      pre += (int)__popcll(kgw & ((1ull << lane) - 1ull));
      int rank = nk0 + pre;
      if (kept && rank < POST_N) {
        float4 v = cbox[tid];
        kbox[rank] = v; karea[rank] = carea[tid];
        ob[rank*5+0] = (float)b;
        ob[rank*5+1] = v.x; ob[rank*5+2] = v.y; ob[rank*5+3] = v.z; ob[rank*5+4] = v.w;
      }
    }
    if (tid == 0) {
      int tot = (int)(__popcll(kgW[0]) + __popcll(kgW[1]) + __popcll(kgW[2]) + __popcll(kgW[3]));
      int nn = nk0 + tot;
      s_nk = nn < POST_N ? nn : POST_N;
    }
    __syncthreads();                                          // B6
    if (s_nk >= POST_N) break;
  }
  __syncthreads();
  int nk = s_nk;
  for (int r = nk + tid; r < POST_N; r += 1024) {
    ob[r*5+0] = (float)b;
    ob[r*5+1] = 0.f; ob[r*5+2] = 0.f; ob[r*5+3] = 0.f; ob[r*5+4] = 0.f;
  }
}

extern "C" void kernel_launch(void* const* d_in, const int* in_sizes, int n_in,
                              void* d_out, int out_size, void* d_ws, size_t ws_size,
                              hipStream_t stream) {
  const float* cls  = (const float*)d_in[0];   // (32, 18, 128, 128)
  const float* dl   = (const float*)d_in[1];   // (32, 36, 128, 128)
  const float* info = (const float*)d_in[2];   // (32, 3)
  float* out = (float*)d_out;                  // (32, 300, 5)
  char* ws = (char*)d_ws;

  // workspace layout (bytes)
  const size_t OFF_KEYS = 0;                        // 32*147456*4 = 18,874,368
  const size_t OFF_H1   = 18874368;                 // 32*4096*4   =    524,288
  const size_t OFF_H2   = 19398656;                 // 32*4096*4   =    524,288
  const size_t OFF_CNT  = 19922944;                 // 32*64*4     =      8,192
  const size_t OFF_CAND = 19931136;                 // 32*8192*8   =  2,097,152
  const size_t OFF_BOX  = 22028288;                 // 32*6000*16  =  3,072,000
  const size_t WS_NEED  = 25100288;
  if (ws_size < WS_NEED) return;

  unsigned* keys  = (unsigned*)(ws + OFF_KEYS);
  unsigned* h1    = (unsigned*)(ws + OFF_H1);
  unsigned* h2    = (unsigned*)(ws + OFF_H2);
  unsigned* cnt   = (unsigned*)(ws + OFF_CNT);
  u64* cand = (u64*)(ws + OFF_CAND);
  float4* boxes   = (float4*)(ws + OFF_BOX);

  // zero h1 + h2 + cnt only (cand masked by cnt in k_sortA)
  hipMemsetAsync(ws + OFF_H1, 0, OFF_CAND - OFF_H1, stream);

  dim3 g1(16, NA, NB);                    // one anchor per block
  k_keys<<<g1, 256, 0, stream>>>(cls, dl, info, keys, h1);
  dim3 gh(8, NB);
  k_hist2<<<gh, 256, 0, stream>>>(keys, h1, h2);
  dim3 gg(GX_GATHER, NB);
  k_gather<<<gg, 256, 0, stream>>>(keys, h1, h2, cnt, cand);
  k_sortA<<<NB * 4, 256, 0, stream>>>(cand, cnt);
  k_sortF<<<NB, 1024, 0, stream>>>(cand, dl, info, boxes);
  k_nms<<<NB, 1024, 0, stream>>>(cand, boxes, out);
}

// Round 8
// 382.636 us; speedup vs baseline: 1.0700x; 1.0700x over previous
//
#include <hip/hip_runtime.h>
#include <cstdint>
#include <cstddef>

#pragma clang fp contract(off)

typedef unsigned long long u64;

#define NB 32
#define NA 9
#define NH 128
#define NW 128
#define HW (NH*NW)            // 16384
#define NANCH (NA*HW)         // 147456
#define PRE_N 6000
#define POST_N 300
#define CAND_CAP 8192
#define NMS_T 0.7f
#define GX_GATHER 24          // blocks per image in k_gather

// Base anchor widths/heights (generate_anchors(16,[.5,1,2],[8,16,32])).
// All anchor centers are at (w*16+8, h*16+8) exactly (fp32-exact integers).
__constant__ float c_wa[9] = {184.f,368.f,736.f,128.f,256.f,512.f,88.f,176.f,352.f};
__constant__ float c_ha[9] = {96.f,192.f,384.f,128.f,256.f,512.f,176.f,352.f,704.f};

__device__ __forceinline__ float4 decode_clip(int a, int h, int w,
    float dx, float dy, float dlw, float dlh, float imh, float imw) {
  float wa = c_wa[a], ha = c_ha[a];
  float cx = (float)w * 16.0f + 8.0f;
  float cy = (float)h * 16.0f + 8.0f;
  float pcx = dx * wa + cx;
  float pcy = dy * ha + cy;
  float pw = expf(dlw) * wa;
  float ph = expf(dlh) * ha;
  float x1 = pcx - 0.5f * pw;
  float y1 = pcy - 0.5f * ph;
  float x2 = pcx + 0.5f * pw;
  float y2 = pcy + 0.5f * ph;
  float4 r;
  r.x = fminf(fmaxf(x1, 0.0f), imw - 1.0f);
  r.y = fminf(fmaxf(y1, 0.0f), imh - 1.0f);
  r.z = fminf(fmaxf(x2, 0.0f), imw - 1.0f);
  r.w = fminf(fmaxf(y2, 0.0f), imh - 1.0f);
  return r;
}

__device__ __forceinline__ unsigned score_key(float sc, float bw, float bh, float msz) {
  unsigned bits = __float_as_uint(sc);
  unsigned key = (bits & 0x80000000u) ? ~bits : (bits | 0x80000000u);
  if (!(bw >= msz && bh >= msz)) key = 0u;   // filtered == score NEG_INF
  return key;
}

// earlier/picked box (p,pa) vs candidate (v,ar):
// reference iou = inter / max(pa + ar - inter, 1e-6)
__device__ __forceinline__ bool sup_test4(float4 v, float ar, float4 p, float pa) {
  float xx1 = fmaxf(p.x, v.x), yy1 = fmaxf(p.y, v.y);
  float xx2 = fminf(p.z, v.z), yy2 = fminf(p.w, v.w);
  float iw = fmaxf(xx2 - xx1 + 1.0f, 0.0f);
  float ih = fmaxf(yy2 - yy1 + 1.0f, 0.0f);
  float inter = iw * ih;
  float iou = inter / fmaxf(pa + ar - inter, 1e-6f);
  return iou > NMS_T;
}

// ---- inline radix-select helpers (256-thread blocks) -----------------------
__device__ void find_B(const unsigned* __restrict__ hb, unsigned* part,
                       unsigned* outB, unsigned* outCum) {
  int tid = threadIdx.x;
  unsigned s = 0;
  for (int i = 0; i < 16; ++i) s += hb[tid*16 + i];
  part[tid] = s;
  __syncthreads();
  for (int off = 1; off < 256; off <<= 1) {
    unsigned v = (tid + off < 256) ? part[tid + off] : 0u;
    __syncthreads();
    part[tid] += v;
    __syncthreads();
  }
  unsigned St = part[tid];
  unsigned Sn = (tid < 255) ? part[tid + 1] : 0u;
  if (St >= (unsigned)PRE_N && Sn < (unsigned)PRE_N) {
    unsigned cum = Sn, B = 0, cumAbove = Sn;
    for (int i = 15; i >= 0; --i) {
      unsigned v = hb[tid*16 + i];
      if (cum + v >= (unsigned)PRE_N) { B = (unsigned)(tid*16 + i); cumAbove = cum; break; }
      cum += v;
    }
    *outB = B; *outCum = cumAbove;
  }
  __syncthreads();
}

__device__ void find_thr(const unsigned* __restrict__ hb2, unsigned B, unsigned cum0,
                         unsigned* part, unsigned* outThr) {
  int tid = threadIdx.x;
  unsigned s = 0;
  for (int i = 0; i < 16; ++i) s += hb2[tid*16 + i];
  part[tid] = s;
  __syncthreads();
  for (int off = 1; off < 256; off <<= 1) {
    unsigned v = (tid + off < 256) ? part[tid + off] : 0u;
    __syncthreads();
    part[tid] += v;
    __syncthreads();
  }
  unsigned St = cum0 + part[tid];
  unsigned Sn = cum0 + ((tid < 255) ? part[tid + 1] : 0u);
  if (St >= (unsigned)PRE_N && Sn < (unsigned)PRE_N) {
    unsigned cum = Sn, t = 1u;
    for (int i = 15; i >= 0; --i) {
      unsigned v = hb2[tid*16 + i];
      if (cum + v >= (unsigned)PRE_N) {
        t = (B << 20) | ((unsigned)(tid*16 + i) << 8);
        break;
      }
      cum += v;
    }
    if (t == 0u) t = 1u;
    *outThr = t;
  }
  __syncthreads();
}

// K1: decode+filter -> order-preserving uint key per anchor, fused coarse
// histogram (key>>20, 4096 bins) aggregated in LDS, flushed per block.
// grid (16, NB): 9216 keys per block -> one dense flush per block.
__global__ __launch_bounds__(256) void k_keys(const float* __restrict__ cls,
    const float* __restrict__ dl, const float* __restrict__ info,
    unsigned* __restrict__ keys, unsigned* __restrict__ hist) {
  __shared__ unsigned hsh[4096];
  int tid = threadIdx.x;
  for (int i = tid; i < 4096; i += 256) hsh[i] = 0;
  int t = blockIdx.x * 256 + tid;            // 0..4095
  int b = blockIdx.y;
  int hw0 = t * 4;                           // 4 consecutive hw, same row
  int h = hw0 >> 7;
  const float* dlb  = dl  + (size_t)b * (4*NA*HW);
  const float* clsb = cls + (size_t)b * (2*NA*HW);
  float imh = info[b*3+0], imw = info[b*3+1];
  float msz = 16.0f * info[b*3+2];
  unsigned* kb = keys + (size_t)b * NANCH;
  __syncthreads();
  #pragma unroll
  for (int a = 0; a < 9; ++a) {
    float4 dx4 = *(const float4*)&dlb[(a*4+0)*HW + hw0];
    float4 dy4 = *(const float4*)&dlb[(a*4+1)*HW + hw0];
    float4 dw4 = *(const float4*)&dlb[(a*4+2)*HW + hw0];
    float4 dh4 = *(const float4*)&dlb[(a*4+3)*HW + hw0];
    float4 sc4 = *(const float4*)&clsb[(NA+a)*HW + hw0];
    uint4 out;
    {
      float4 bx = decode_clip(a, h, (hw0+0)&127, dx4.x, dy4.x, dw4.x, dh4.x, imh, imw);
      out.x = score_key(sc4.x, bx.z-bx.x+1.0f, bx.w-bx.y+1.0f, msz);
    }
    {
      float4 bx = decode_clip(a, h, (hw0+1)&127, dx4.y, dy4.y, dw4.y, dh4.y, imh, imw);
      out.y = score_key(sc4.y, bx.z-bx.x+1.0f, bx.w-bx.y+1.0f, msz);
    }
    {
      float4 bx = decode_clip(a, h, (hw0+2)&127, dx4.z, dy4.z, dw4.z, dh4.z, imh, imw);
      out.z = score_key(sc4.z, bx.z-bx.x+1.0f, bx.w-bx.y+1.0f, msz);
    }
    {
      float4 bx = decode_clip(a, h, (hw0+3)&127, dx4.w, dy4.w, dw4.w, dh4.w, imh, imw);
      out.w = score_key(sc4.w, bx.z-bx.x+1.0f, bx.w-bx.y+1.0f, msz);
    }
    *(uint4*)&kb[a*HW + hw0] = out;
    atomicAdd(&hsh[out.x >> 20], 1u);
    atomicAdd(&hsh[out.y >> 20], 1u);
    atomicAdd(&hsh[out.z >> 20], 1u);
    atomicAdd(&hsh[out.w >> 20], 1u);
  }
  __syncthreads();
  unsigned* gb = hist + ((size_t)b << 12);
  for (int i = tid; i < 4096; i += 256) {
    unsigned v = hsh[i];
    if (v) atomicAdd(&gb[i], v);
  }
}

// K2: refine histogram — bits[19:8] of keys whose top-12 == B (B inline from h1).
__global__ __launch_bounds__(256) void k_hist2(const unsigned* __restrict__ keys,
    const unsigned* __restrict__ hist1, unsigned* __restrict__ hist2) {
  __shared__ unsigned h[4096];
  __shared__ unsigned part[256];
  __shared__ unsigned sB, sCum;
  int b = blockIdx.y, tid = threadIdx.x;
  for (int i = tid; i < 4096; i += 256) h[i] = 0;
  __syncthreads();
  find_B(hist1 + ((size_t)b << 12), part, &sB, &sCum);
  unsigned B = sB;
  const unsigned* kb = keys + (size_t)b * NANCH;
  for (int i = blockIdx.x * 256 + tid; i < NANCH; i += gridDim.x * 256) {
    unsigned k = kb[i];
    if ((k >> 20) == B) atomicAdd(&h[(k >> 8) & 4095u], 1u);
  }
  __syncthreads();
  unsigned* gb = hist2 + ((size_t)b << 12);
  for (int i = tid; i < 4096; i += 256) { unsigned v = h[i]; if (v) atomicAdd(&gb[i], v); }
}

// K3: gather (key, ~origidx) for key >= thr (thr inline from h1+h2).
__global__ __launch_bounds__(256) void k_gather(const unsigned* __restrict__ keys,
    const unsigned* __restrict__ hist1, const unsigned* __restrict__ hist2,
    unsigned* __restrict__ cnt, u64* __restrict__ cand) {
  int b = blockIdx.y, tid = threadIdx.x;
  int lane = tid & 63, wv = tid >> 6;
  __shared__ unsigned part[256];
  __shared__ unsigned sB, sCum, sThr;
  __shared__ unsigned wcnt[4], woff[4], blkbase;
  if (tid == 0) sThr = 1u;
  __syncthreads();
  find_B(hist1 + ((size_t)b << 12), part, &sB, &sCum);
  find_thr(hist2 + ((size_t)b << 12), sB, sCum, part, &sThr);
  unsigned t_ = sThr;
  const unsigned* kb = keys + (size_t)b * NANCH;
  u64* cb = cand + (size_t)b * CAND_CAP;
  unsigned* cp = cnt + (size_t)b * 64;
  const int PER_BLK = NANCH / GX_GATHER;      // 6144
  int base0 = blockIdx.x * PER_BLK;
  for (int it = 0; it < PER_BLK / 256; ++it) {
    int j = base0 + it * 256 + tid;
    unsigned key = kb[j];
    bool pass = key >= t_;
    u64 mask = __ballot(pass);
    if (lane == 0) wcnt[wv] = (unsigned)__popcll(mask);
    __syncthreads();
    if (tid == 0) {
      unsigned s0 = 0;
      for (int w = 0; w < 4; ++w) { woff[w] = s0; s0 += wcnt[w]; }
      blkbase = s0 ? atomicAdd(cp, s0) : 0u;
    }
    __syncthreads();
    if (pass) {
      unsigned pos = blkbase + woff[wv] + (unsigned)__popcll(mask & ((1ull << lane) - 1ull));
      if (pos < CAND_CAP) {
        int a = j >> 14, hw = j & (HW - 1);
        unsigned oi = (unsigned)(hw * 9 + a);
        cb[pos] = ((u64)key << 32) | (unsigned)(~oi);
      }
    }
    __syncthreads();
  }
}

// K4: local sort of 2048-chunks (masks unwritten slots to 0 via cnt).
// 128 blocks. Chunk c: desc iff c even.
__global__ __launch_bounds__(256) void k_sortA(u64* __restrict__ cand,
                                               const unsigned* __restrict__ cnt) {
  __shared__ u64 sm[2048];   // 16 KiB
  int blk = blockIdx.x;
  int b = blk >> 2, c = blk & 3;
  unsigned effcnt = cnt[b * 64];
  if (effcnt > CAND_CAP) effcnt = CAND_CAP;
  u64* cb = cand + (size_t)b * CAND_CAP + (size_t)c * 2048;
  int base = c * 2048;
  int tid = threadIdx.x;
  for (int t = tid; t < 2048; t += 256)
    sm[t] = ((unsigned)(base + t) < effcnt) ? cb[t] : 0ull;
  bool blkdesc = (c & 1) == 0;
  for (int k = 2; k <= 2048; k <<= 1) {
    for (int j = k >> 1; j > 0; j >>= 1) {
      __syncthreads();
      for (int t = tid; t < 2048; t += 256) {
        int p = t ^ j;
        if (p > t) {
          bool up = (k == 2048) ? blkdesc : ((t & k) == 0);
          u64 x = sm[t], y = sm[p];
          if (up ? (x < y) : (x > y)) { sm[t] = y; sm[p] = x; }
        }
      }
    }
  }
  __syncthreads();
  for (int t = tid; t < 2048; t += 256) cb[t] = sm[t];
}

// K5: bitonic merge of 4096-blocks; block m desc iff m even. 64 blocks.
__global__ __launch_bounds__(512) void k_merge4096(u64* __restrict__ cand) {
  __shared__ u64 sm[4096];   // 32 KiB
  int blk = blockIdx.x;
  int b = blk >> 1, m = blk & 1;
  u64* cb = cand + (size_t)b * CAND_CAP + (size_t)m * 4096;
  int tid = threadIdx.x;
  for (int t = tid; t < 4096; t += 512) sm[t] = cb[t];
  bool desc = (m & 1) == 0;
  for (int j = 2048; j > 0; j >>= 1) {
    __syncthreads();
    for (int t = tid; t < 4096; t += 512) {
      int p = t ^ j;
      if (p > t) {
        u64 x = sm[t], y = sm[p];
        if (desc ? (x < y) : (x > y)) { sm[t] = y; sm[p] = x; }
      }
    }
  }
  __syncthreads();
  for (int t = tid; t < 4096; t += 512) cb[t] = sm[t];
}

// K6: FUSED final merge (k=8192 desc, 13 phases, in LDS) + greedy NMS.
// Sorted candidates stay in LDS; boxes decoded on the fly per 256-chunk.
__global__ __launch_bounds__(1024) void k_final(const u64* __restrict__ cand,
    const float* __restrict__ dl, const float* __restrict__ info,
    float* __restrict__ out) {
  __shared__ u64 sm[CAND_CAP];   // 64 KiB — sorted candidate keys
  __shared__ float4 kbox[POST_N];
  __shared__ float  karea[POST_N];
  __shared__ float4 cbox[256];
  __shared__ float  carea[256];
  __shared__ unsigned supf[256];
  __shared__ u64 sup[256][4];
  __shared__ u64 aliveM[4];
  __shared__ u64 kgW[4];
  __shared__ int s_nk;
  int b = blockIdx.x, tid = threadIdx.x;
  int c = tid & 255, seg = tid >> 8;
  int lane = tid & 63, wv = tid >> 6;
  int cg = c >> 6;
  if (tid == 0) s_nk = 0;
  const u64* cb = cand + (size_t)b * CAND_CAP;
  for (int t = tid; t < CAND_CAP; t += 1024) sm[t] = cb[t];
  // final merge: k = 8192, all-descending
  for (int j = CAND_CAP >> 1; j > 0; j >>= 1) {
    __syncthreads();
    for (int t = tid; t < CAND_CAP; t += 1024) {
      int p = t ^ j;
      if (p > t) {
        u64 x = sm[t], y = sm[p];
        if (x < y) { sm[t] = y; sm[p] = x; }
      }
    }
  }
  __syncthreads();

  const float* dlb = dl + (size_t)b * (4*NA*HW);
  float imh = info[b*3+0], imw = info[b*3+1];
  float* ob = out + (size_t)b * (POST_N * 5);
  volatile unsigned* svf = supf;

  for (int base = 0; base < PRE_N; base += 256) {
    // load chunk + decode boxes on the fly (first 256 threads)
    if (tid < 256) {
      int i = base + tid;
      u64 ck = (i < PRE_N) ? sm[i] : 0ull;
      bool valid = (unsigned)(ck >> 32) != 0u;
      float4 v = make_float4(0.f, 0.f, 0.f, 0.f);
      if (valid) {
        int idx = (int)(~(unsigned)(ck & 0xFFFFFFFFull));
        int a = idx % 9, hw = idx / 9;
        v = decode_clip(a, hw >> 7, hw & 127,
                        dlb[(a*4+0)*HW + hw], dlb[(a*4+1)*HW + hw],
                        dlb[(a*4+2)*HW + hw], dlb[(a*4+3)*HW + hw], imh, imw);
      }
      cbox[tid] = v;
      carea[tid] = (v.z - v.x + 1.0f) * (v.w - v.y + 1.0f);
      supf[tid] = valid ? 0u : 1u;
    }
    __syncthreads();                                          // B1
    int nk0 = s_nk;

    // pre-filter vs kept list: 4-way split of depth, cross-segment poll
    if (supf[c] == 0u) {
      float4 v = cbox[c]; float ar = carea[c];
      for (int k = seg; k < nk0; k += 4) {
        if (svf[c]) break;
        if (sup_test4(v, ar, kbox[k], karea[k])) { atomicOr(&supf[c], 1u); break; }
      }
    }
    __syncthreads();                                          // B2

    if (seg == 0) {
      u64 am = __ballot(supf[c] == 0u);
      if (lane == 0) aliveM[wv] = am;
    }
    __syncthreads();                                          // B3
    if ((aliveM[0] | aliveM[1] | aliveM[2] | aliveM[3]) == 0ull) continue;

    // intra-chunk suppression matrix
    if (supf[c] == 0u && seg <= cg) {
      float4 v = cbox[c]; float ar = carea[c];
      u64 m = aliveM[seg];
      if (seg == cg) m &= (1ull << (c & 63)) - 1ull;
      u64 r = 0;
      while (m) {
        int j = __builtin_ctzll(m);
        m &= m - 1;
        int col = seg * 64 + j;
        if (sup_test4(v, ar, cbox[col], carea[col])) r |= 1ull << j;
      }
      sup[c][seg] = r;
    }
    __syncthreads();                                          // B4

    // resolve by wave 0
    if (wv == 0) {
      u64 kw0 = 0, kw1 = 0, kw2 = 0, kw3 = 0;
      {
        bool a = (aliveM[0] >> lane) & 1;
        u64 r = a ? sup[lane][0] : 0;
        u64 cm = __ballot(a), kg = 0;
        while (cm) {
          int j = __builtin_ctzll(cm);
          kg |= 1ull << j;
          u64 rem = __ballot((r >> j) & 1);
          cm &= ~(rem | (1ull << j));
        }
        kw0 = kg;
      }
      {
        int cc = 64 + lane;
        bool a = (aliveM[1] >> lane) & 1;
        if (a) a = (sup[cc][0] & kw0) == 0;
        u64 r = a ? sup[cc][1] : 0;
        u64 cm = __ballot(a), kg = 0;
        while (cm) {
          int j = __builtin_ctzll(cm);
          kg |= 1ull << j;
          u64 rem = __ballot((r >> j) & 1);
          cm &= ~(rem | (1ull << j));
        }
        kw1 = kg;
      }
      {
        int cc = 128 + lane;
        bool a = (aliveM[2] >> lane) & 1;
        if (a) a = ((sup[cc][0] & kw0) == 0) && ((sup[cc][1] & kw1) == 0);
        u64 r = a ? sup[cc][2] : 0;
        u64 cm = __ballot(a), kg = 0;
        while (cm) {
          int j = __builtin_ctzll(cm);
          kg |= 1ull << j;
          u64 rem = __ballot((r >> j) & 1);
          cm &= ~(rem | (1ull << j));
        }
        kw2 = kg;
      }
      {
        int cc = 192 + lane;
        bool a = (aliveM[3] >> lane) & 1;
        if (a) a = ((sup[cc][0] & kw0) == 0) && ((sup[cc][1] & kw1) == 0) &&
                   ((sup[cc][2] & kw2) == 0);
        u64 r = a ? sup[cc][3] : 0;
        u64 cm = __ballot(a), kg = 0;
        while (cm) {
          int j = __builtin_ctzll(cm);
          kg |= 1ull << j;
          u64 rem = __ballot((r >> j) & 1);
          cm &= ~(rem | (1ull << j));
        }
        kw3 = kg;
      }
      if (lane == 0) { kgW[0] = kw0; kgW[1] = kw1; kgW[2] = kw2; kgW[3] = kw3; }
    }
    __syncthreads();                                          // B5

    // append kept boxes + update s_nk
    if (tid < 256) {
      u64 kgw = kgW[wv];
      bool kept = (kgw >> lane) & 1;
      int pre = 0;
      for (int g = 0; g < wv; ++g) pre += (int)__popcll(kgW[g]);
      pre += (int)__popcll(kgw & ((1ull << lane) - 1ull));
      int rank = nk0 + pre;
      if (kept && rank < POST_N) {
        float4 v = cbox[tid];
        kbox[rank] = v; karea[rank] = carea[tid];
        ob[rank*5+0] = (float)b;
        ob[rank*5+1] = v.x; ob[rank*5+2] = v.y; ob[rank*5+3] = v.z; ob[rank*5+4] = v.w;
      }
    }
    if (tid == 0) {
      int tot = (int)(__popcll(kgW[0]) + __popcll(kgW[1]) + __popcll(kgW[2]) + __popcll(kgW[3]));
      int nn = nk0 + tot;
      s_nk = nn < POST_N ? nn : POST_N;
    }
    __syncthreads();                                          // B6
    if (s_nk >= POST_N) break;
  }
  __syncthreads();
  int nk = s_nk;
  for (int r = nk + tid; r < POST_N; r += 1024) {
    ob[r*5+0] = (float)b;
    ob[r*5+1] = 0.f; ob[r*5+2] = 0.f; ob[r*5+3] = 0.f; ob[r*5+4] = 0.f;
  }
}

extern "C" void kernel_launch(void* const* d_in, const int* in_sizes, int n_in,
                              void* d_out, int out_size, void* d_ws, size_t ws_size,
                              hipStream_t stream) {
  const float* cls  = (const float*)d_in[0];   // (32, 18, 128, 128)
  const float* dl   = (const float*)d_in[1];   // (32, 36, 128, 128)
  const float* info = (const float*)d_in[2];   // (32, 3)
  float* out = (float*)d_out;                  // (32, 300, 5)
  char* ws = (char*)d_ws;

  // workspace layout (bytes)
  const size_t OFF_KEYS = 0;                        // 32*147456*4 = 18,874,368
  const size_t OFF_H1   = 18874368;                 // 32*4096*4   =    524,288
  const size_t OFF_H2   = 19398656;                 // 32*4096*4   =    524,288
  const size_t OFF_CNT  = 19922944;                 // 32*64*4     =      8,192
  const size_t OFF_CAND = 19931136;                 // 32*8192*8   =  2,097,152
  const size_t WS_NEED  = 22028288;
  if (ws_size < WS_NEED) return;

  unsigned* keys  = (unsigned*)(ws + OFF_KEYS);
  unsigned* h1    = (unsigned*)(ws + OFF_H1);
  unsigned* h2    = (unsigned*)(ws + OFF_H2);
  unsigned* cnt   = (unsigned*)(ws + OFF_CNT);
  u64* cand = (u64*)(ws + OFF_CAND);

  // zero h1 + h2 + cnt only (cand masked by cnt in k_sortA)
  hipMemsetAsync(ws + OFF_H1, 0, OFF_CAND - OFF_H1, stream);

  dim3 g1(HW / 1024, NB);                 // (16, 32)
  k_keys<<<g1, 256, 0, stream>>>(cls, dl, info, keys, h1);
  dim3 gh(8, NB);
  k_hist2<<<gh, 256, 0, stream>>>(keys, h1, h2);
  dim3 gg(GX_GATHER, NB);
  k_gather<<<gg, 256, 0, stream>>>(keys, h1, h2, cnt, cand);
  k_sortA<<<NB * 4, 256, 0, stream>>>(cand, cnt);
  k_merge4096<<<NB * 2, 512, 0, stream>>>(cand);
  k_final<<<NB, 1024, 0, stream>>>(cand, dl, info, out);
}